// Round 1
// baseline (335.221 us; speedup 1.0000x reference)
//
#include <hip/hip_runtime.h>
#include <hip/hip_bf16.h>

constexpr int NV  = 1024;   // nodes
constexpr int EV  = 16384;  // edges
constexpr int FIN = 128;
constexpr int HD  = 64;

// ---------------- small precompute: ew_mean, c1, c2 ----------------
__global__ __launch_bounds__(256) void k_prescalar(
    const float* __restrict__ ew,
    const float* __restrict__ we1, const float* __restrict__ ae1,
    const float* __restrict__ we2, const float* __restrict__ ae2,
    float* __restrict__ scal)
{
    __shared__ float red[256];
    float s = 0.f;
    for (int i = threadIdx.x; i < EV; i += 256) s += ew[i];
    red[threadIdx.x] = s; __syncthreads();
    for (int w = 128; w; w >>= 1) {
        if (threadIdx.x < w) red[threadIdx.x] += red[threadIdx.x + w];
        __syncthreads();
    }
    if (threadIdx.x == 0) {
        scal[0] = red[0] / (float)EV;
        float c1 = 0.f, c2 = 0.f;
        for (int k = 0; k < HD; k++) { c1 += we1[k]*ae1[k]; c2 += we2[k]*ae2[k]; }
        scal[1] = c1; scal[2] = c2;
    }
}

// ---------------- GCN degree (real edges; +1 self-loop folded into dinv) ----
__global__ __launch_bounds__(256) void k_deg(const int* __restrict__ dst, float* __restrict__ deg)
{
    int t = blockIdx.x*256 + threadIdx.x;
    if (t < EV) atomicAdd(&deg[dst[t]], 1.0f);
}

__global__ __launch_bounds__(256) void k_dinv(const float* __restrict__ deg, float* __restrict__ dinv)
{
    int t = blockIdx.x*256 + threadIdx.x;
    if (t < NV) dinv[t] = rsqrtf(deg[t] + 1.0f);   // +1 = self-loop
}

// ---------------- dense matmul h = x@W  (+ GCN self-loop init) -------------
__global__ __launch_bounds__(256) void k_mm_gcn(
    const float* __restrict__ x, const float* __restrict__ W,
    const float* __restrict__ dinv, float* __restrict__ h,
    float* __restrict__ outacc, int K)
{
    int t = blockIdx.x*256 + threadIdx.x;       // NV*HD threads
    int i = t >> 6, j = t & 63;
    float acc = 0.f;
    for (int k = 0; k < K; k++) acc = fmaf(x[i*K+k], W[k*HD+j], acc);
    h[t] = acc;
    float dv = dinv[i];
    outacc[t] = dv*dv*acc;                       // self-loop contribution
}

__global__ __launch_bounds__(256) void k_mm(
    const float* __restrict__ x, const float* __restrict__ W,
    float* __restrict__ h, int K)
{
    int t = blockIdx.x*256 + threadIdx.x;
    int i = t >> 6, j = t & 63;
    float acc = 0.f;
    for (int k = 0; k < K; k++) acc = fmaf(x[i*K+k], W[k*HD+j], acc);
    h[t] = acc;
}

// GCN3: input is 0.7*xa2 + 0.3*xd2, fused
__global__ __launch_bounds__(256) void k_mm_gcn3(
    const float* __restrict__ xa, const float* __restrict__ xd,
    const float* __restrict__ W, const float* __restrict__ dinv,
    float* __restrict__ h, float* __restrict__ outacc)
{
    int t = blockIdx.x*256 + threadIdx.x;
    int i = t >> 6, j = t & 63;
    float acc = 0.f;
    for (int k = 0; k < HD; k++) {
        float xv = 0.7f*xa[i*HD+k] + 0.3f*xd[i*HD+k];
        acc = fmaf(xv, W[k*HD+j], acc);
    }
    h[t] = acc;
    float dv = dinv[i];
    outacc[t] = dv*dv*acc;
}

// ---------------- GCN edge scatter -----------------------------------------
__global__ __launch_bounds__(256) void k_gcn_scatter(
    const int* __restrict__ src, const int* __restrict__ dst,
    const float* __restrict__ dinv, const float* __restrict__ h,
    float* __restrict__ out)
{
    int t = blockIdx.x*256 + threadIdx.x;       // EV*HD threads
    int e = t >> 6, k = t & 63;
    int s = src[e], d = dst[e];
    float v = dinv[s]*dinv[d]*h[s*HD+k];
    atomicAdd(&out[d*HD+k], v);
}

__global__ __launch_bounds__(256) void k_bias_relu(
    float* __restrict__ out, const float* __restrict__ b)
{
    int t = blockIdx.x*256 + threadIdx.x;       // NV*HD
    out[t] = fmaxf(out[t] + b[t & 63], 0.f);
}

// ---------------- GAT ------------------------------------------------------
// per-node attention logits: al_s[i] = h[i,:]·a_src, al_d[i] = h[i,:]·a_dst
__global__ __launch_bounds__(256) void k_al(
    const float* __restrict__ h, const float* __restrict__ asrc,
    const float* __restrict__ adst, float* __restrict__ al_s,
    float* __restrict__ al_d)
{
    int gt = blockIdx.x*256 + threadIdx.x;
    int node = gt >> 6, lane = gt & 63;
    float v = h[node*HD + lane];
    float ps = v * asrc[lane];
    float pd = v * adst[lane];
    for (int off = 32; off; off >>= 1) {
        ps += __shfl_down(ps, off, 64);
        pd += __shfl_down(pd, off, 64);
    }
    if (lane == 0) { al_s[node] = ps; al_d[node] = pd; }
}

__device__ __forceinline__ unsigned fenc(float f) {
    unsigned b = __float_as_uint(f);
    return (b & 0x80000000u) ? ~b : (b | 0x80000000u);
}
__device__ __forceinline__ float fdec(unsigned u) {
    return __uint_as_float((u & 0x80000000u) ? (u & 0x7FFFFFFFu) : ~u);
}

// e = leaky_relu(al_s[s]+al_d[d]+ew*c), segment max at d (encoded atomicMax)
__global__ __launch_bounds__(256) void k_gat_edge(
    const int* __restrict__ src, const int* __restrict__ dst,
    const float* __restrict__ ew, const float* __restrict__ al_s,
    const float* __restrict__ al_d, const float* __restrict__ scal,
    int cidx, float* __restrict__ ebuf, unsigned* __restrict__ emax)
{
    int e = blockIdx.x*256 + threadIdx.x;       // EV+NV threads
    int s, d; float w;
    if (e < EV) { s = src[e]; d = dst[e]; w = ew[e]; }
    else        { s = d = e - EV; w = scal[0]; }
    float x = al_s[s] + al_d[d] + w * scal[cidx];
    float lr = (x > 0.f) ? x : 0.2f * x;
    ebuf[e] = lr;
    atomicMax(&emax[d], fenc(lr));
}

__global__ __launch_bounds__(256) void k_gat_exp(
    const int* __restrict__ dst, const float* __restrict__ ebuf,
    const unsigned* __restrict__ emax, float* __restrict__ exbuf,
    float* __restrict__ denom)
{
    int e = blockIdx.x*256 + threadIdx.x;       // EV+NV
    int d = (e < EV) ? dst[e] : (e - EV);
    float ex = expf(ebuf[e] - fdec(emax[d]));
    exbuf[e] = ex;
    atomicAdd(&denom[d], ex);
}

__global__ __launch_bounds__(256) void k_gat_scatter(
    const int* __restrict__ src, const int* __restrict__ dst,
    const float* __restrict__ h, const float* __restrict__ exbuf,
    const float* __restrict__ denom, float* __restrict__ out)
{
    int t = blockIdx.x*256 + threadIdx.x;       // (EV+NV)*HD
    int e = t >> 6, k = t & 63;
    int s, d;
    if (e < EV) { s = src[e]; d = dst[e]; }
    else        { s = d = e - EV; }
    float alpha = exbuf[e] / denom[d];
    atomicAdd(&out[d*HD+k], alpha * h[s*HD+k]);
}

// ---------------- predictor -------------------------------------------------
// h1 = h@Wp1[:H] + bp1 ; h2 = h@Wp1[H:]
__global__ __launch_bounds__(256) void k_pred(
    const float* __restrict__ h, const float* __restrict__ Wp1,
    const float* __restrict__ bp1, float* __restrict__ h1,
    float* __restrict__ h2)
{
    int t = blockIdx.x*256 + threadIdx.x;       // NV*HD
    int i = t >> 6, j = t & 63;
    float a1 = 0.f, a2 = 0.f;
    for (int k = 0; k < HD; k++) {
        float xv = h[i*HD+k];
        a1 = fmaf(xv, Wp1[k*HD + j], a1);
        a2 = fmaf(xv, Wp1[(HD + k)*HD + j], a2);
    }
    h1[t] = a1 + bp1[j];
    h2[t] = a2;
}

__global__ __launch_bounds__(256) void k_pairs(
    const float* __restrict__ h1, const float* __restrict__ h2,
    const float* __restrict__ w2, const float* __restrict__ bp2,
    float* __restrict__ out)
{
    __shared__ float s1[16][65], s2[16][65], w2s[64];
    int tid = threadIdx.y*16 + threadIdx.x;
    int i0 = blockIdx.y*16, j0 = blockIdx.x*16;
    for (int r = tid; r < 16*64; r += 256) {
        int row = r >> 6, col = r & 63;
        s1[row][col] = h1[(i0+row)*HD + col];
        s2[row][col] = h2[(j0+row)*HD + col];
    }
    if (tid < 64) w2s[tid] = w2[tid];
    __syncthreads();
    const float* a = s1[threadIdx.y];
    const float* b = s2[threadIdx.x];
    float acc = 0.f;
    #pragma unroll
    for (int k = 0; k < 64; k++) {
        float v = a[k] + b[k];
        acc = fmaf(fmaxf(v, 0.f), w2s[k], acc);
    }
    float logit = acc + bp2[0];
    out[(i0+threadIdx.y)*NV + (j0+threadIdx.x)] = 1.f/(1.f + expf(-logit));
}

// ---------------------------------------------------------------------------
extern "C" void kernel_launch(void* const* d_in, const int* in_sizes, int n_in,
                              void* d_out, int out_size, void* d_ws, size_t ws_size,
                              hipStream_t stream)
{
    const float* x      = (const float*)d_in[0];
    const int*   ei_a   = (const int*)d_in[1];
    const int*   ei_d   = (const int*)d_in[2];
    const float* ew     = (const float*)d_in[3];
    const float* Wg1    = (const float*)d_in[4];
    const float* bg1    = (const float*)d_in[5];
    const float* Wt1    = (const float*)d_in[6];
    const float* as1    = (const float*)d_in[7];
    const float* ad1    = (const float*)d_in[8];
    const float* we1    = (const float*)d_in[9];
    const float* ae1    = (const float*)d_in[10];
    const float* bt1    = (const float*)d_in[11];
    const float* Wg2    = (const float*)d_in[12];
    const float* bg2    = (const float*)d_in[13];
    const float* Wt2    = (const float*)d_in[14];
    const float* as2    = (const float*)d_in[15];
    const float* ad2    = (const float*)d_in[16];
    const float* we2    = (const float*)d_in[17];
    const float* ae2    = (const float*)d_in[18];
    const float* bt2    = (const float*)d_in[19];
    const float* Wg3    = (const float*)d_in[20];
    const float* bg3    = (const float*)d_in[21];
    const float* Wp1    = (const float*)d_in[22];
    const float* bp1    = (const float*)d_in[23];
    const float* Wp2    = (const float*)d_in[24];
    const float* bp2    = (const float*)d_in[25];
    float* out = (float*)d_out;

    const int* sa = ei_a;            // edge_index_above[0]
    const int* da = ei_a + EV;       // edge_index_above[1]
    const int* sd = ei_d;
    const int* dd = ei_d + EV;

    // workspace layout (floats)
    float* W = (float*)d_ws;
    float*    deg   = W;                    // 1024
    float*    dinv  = W + 1024;             // 1024
    float*    scal  = W + 2048;             // 8
    float*    al_s  = W + 2056;             // 1024
    float*    al_d  = W + 3080;             // 1024
    unsigned* emax  = (unsigned*)(W + 4104);// 1024
    float*    denom = W + 5128;             // 1024
    float*    ebuf  = W + 6152;             // 17408
    float*    exbuf = W + 23560;            // 17408
    float*    h     = W + 40968;            // 65536
    float*    xa1   = W + 106504;           // 65536
    float*    xd1   = W + 172040;           // 65536
    float*    xa2   = W + 237576;           // 65536
    float*    xd2   = W + 303112;           // 65536
    float*    hfin  = W + 368648;           // 65536
    float*    h1    = W + 434184;           // 65536
    float*    h2    = W + 499720;           // 65536

    const int NB_NH = NV*HD/256;            // 256 blocks for N*H work
    const int NB_EH = EV*HD/256;            // 4096 blocks
    const int NB_E1 = (EV+NV)/256;          // 68
    const int NB_EH1 = (EV+NV)*HD/256;      // 4352

    hipMemsetAsync(deg, 0, NV*sizeof(float), stream);
    k_prescalar<<<1, 256, 0, stream>>>(ew, we1, ae1, we2, ae2, scal);
    k_deg<<<EV/256, 256, 0, stream>>>(da, deg);
    k_dinv<<<NV/256, 256, 0, stream>>>(deg, dinv);

    // ---- GCN1: x -> xa1
    k_mm_gcn<<<NB_NH, 256, 0, stream>>>(x, Wg1, dinv, h, xa1, FIN);
    k_gcn_scatter<<<NB_EH, 256, 0, stream>>>(sa, da, dinv, h, xa1);
    k_bias_relu<<<NB_NH, 256, 0, stream>>>(xa1, bg1);

    // ---- GAT1: x -> xd1
    k_mm<<<NB_NH, 256, 0, stream>>>(x, Wt1, h, FIN);
    k_al<<<NB_NH, 256, 0, stream>>>(h, as1, ad1, al_s, al_d);
    hipMemsetAsync(emax, 0, NV*sizeof(unsigned), stream);
    hipMemsetAsync(denom, 0, NV*sizeof(float), stream);
    hipMemsetAsync(xd1, 0, NV*HD*sizeof(float), stream);
    k_gat_edge<<<NB_E1, 256, 0, stream>>>(sd, dd, ew, al_s, al_d, scal, 1, ebuf, emax);
    k_gat_exp<<<NB_E1, 256, 0, stream>>>(dd, ebuf, emax, exbuf, denom);
    k_gat_scatter<<<NB_EH1, 256, 0, stream>>>(sd, dd, h, exbuf, denom, xd1);
    k_bias_relu<<<NB_NH, 256, 0, stream>>>(xd1, bt1);

    // ---- GCN2: xa1 -> xa2
    k_mm_gcn<<<NB_NH, 256, 0, stream>>>(xa1, Wg2, dinv, h, xa2, HD);
    k_gcn_scatter<<<NB_EH, 256, 0, stream>>>(sa, da, dinv, h, xa2);
    k_bias_relu<<<NB_NH, 256, 0, stream>>>(xa2, bg2);

    // ---- GAT2: xd1 -> xd2
    k_mm<<<NB_NH, 256, 0, stream>>>(xd1, Wt2, h, HD);
    k_al<<<NB_NH, 256, 0, stream>>>(h, as2, ad2, al_s, al_d);
    hipMemsetAsync(emax, 0, NV*sizeof(unsigned), stream);
    hipMemsetAsync(denom, 0, NV*sizeof(float), stream);
    hipMemsetAsync(xd2, 0, NV*HD*sizeof(float), stream);
    k_gat_edge<<<NB_E1, 256, 0, stream>>>(sd, dd, ew, al_s, al_d, scal, 2, ebuf, emax);
    k_gat_exp<<<NB_E1, 256, 0, stream>>>(dd, ebuf, emax, exbuf, denom);
    k_gat_scatter<<<NB_EH1, 256, 0, stream>>>(sd, dd, h, exbuf, denom, xd2);
    k_bias_relu<<<NB_NH, 256, 0, stream>>>(xd2, bt2);

    // ---- GCN3 (fused 0.7*xa2+0.3*xd2): -> hfin
    k_mm_gcn3<<<NB_NH, 256, 0, stream>>>(xa2, xd2, Wg3, dinv, h, hfin);
    k_gcn_scatter<<<NB_EH, 256, 0, stream>>>(sa, da, dinv, h, hfin);
    k_bias_relu<<<NB_NH, 256, 0, stream>>>(hfin, bg3);

    // ---- predictor
    k_pred<<<NB_NH, 256, 0, stream>>>(hfin, Wp1, bp1, h1, h2);
    k_pairs<<<dim3(NV/16, NV/16), dim3(16, 16), 0, stream>>>(h1, h2, Wp2, bp2, out);
}

// Round 2
// 205.697 us; speedup vs baseline: 1.6297x; 1.6297x over previous
//
#include <hip/hip_runtime.h>

constexpr int NV  = 1024;   // nodes
constexpr int EV  = 16384;  // edges
constexpr int FIN = 128;
constexpr int HD  = 64;

__device__ __forceinline__ float relu_(float v){ return fmaxf(v, 0.f); }

// ---------------- degree of dst (real edges only) --------------------------
__global__ __launch_bounds__(256) void k_deg(const int* __restrict__ dst, float* __restrict__ deg)
{
    int t = blockIdx.x*256 + threadIdx.x;   // exactly EV threads
    atomicAdd(&deg[dst[t]], 1.0f);
}

// ---------------- scalars (ew_mean, c1, c2) + dinv -------------------------
__global__ __launch_bounds__(256) void k_pre(
    const float* __restrict__ ew,
    const float* __restrict__ we1, const float* __restrict__ ae1,
    const float* __restrict__ we2, const float* __restrict__ ae2,
    const float* __restrict__ deg, float* __restrict__ scal, float* __restrict__ dinv)
{
    __shared__ float red[256];
    float s = 0.f;
    for (int i = threadIdx.x; i < EV; i += 256) s += ew[i];
    red[threadIdx.x] = s; __syncthreads();
    for (int w = 128; w; w >>= 1) {
        if (threadIdx.x < w) red[threadIdx.x] += red[threadIdx.x + w];
        __syncthreads();
    }
    if (threadIdx.x == 0) {
        scal[0] = red[0] / (float)EV;
        float c1 = 0.f, c2 = 0.f;
        for (int k = 0; k < HD; k++) { c1 += we1[k]*ae1[k]; c2 += we2[k]*ae2[k]; }
        scal[1] = c1; scal[2] = c2;
    }
    for (int i = threadIdx.x; i < NV; i += 256) dinv[i] = rsqrtf(deg[i] + 1.0f);
}

// ---------------- GCN matmul: h = act(x)@W, outacc = dinv^2 * h ------------
// act = FUSEIN ? relu(x + bin) : x   (bias+relu of the producing layer folded in)
template<int K, bool FUSEIN>
__global__ __launch_bounds__(256) void k_mm_gcn_t(
    const float* __restrict__ x, const float* __restrict__ bin,
    const float* __restrict__ W, const float* __restrict__ dinv,
    float* __restrict__ h, float* __restrict__ outacc)
{
    __shared__ float4 Ws[K*16];             // K x 64 floats
    int tid = threadIdx.x;
    for (int r = tid; r < K*16; r += 256) Ws[r] = ((const float4*)W)[r];
    __syncthreads();
    int t = blockIdx.x*256 + tid;
    int i = t >> 6, j = t & 63;
    const float4* xr = (const float4*)(x + i*K);
    const float4* bv = (const float4*)bin;
    const float*  Wf = (const float*)Ws;
    float acc = 0.f;
    #pragma unroll
    for (int k4 = 0; k4 < K/4; k4++) {
        float4 xv = xr[k4];
        if constexpr (FUSEIN) {
            float4 b = bv[k4];
            xv.x = relu_(xv.x+b.x); xv.y = relu_(xv.y+b.y);
            xv.z = relu_(xv.z+b.z); xv.w = relu_(xv.w+b.w);
        }
        acc = fmaf(xv.x, Wf[(4*k4+0)*64 + j], acc);
        acc = fmaf(xv.y, Wf[(4*k4+1)*64 + j], acc);
        acc = fmaf(xv.z, Wf[(4*k4+2)*64 + j], acc);
        acc = fmaf(xv.w, Wf[(4*k4+3)*64 + j], acc);
    }
    h[t] = acc;
    float dv = dinv[i];
    outacc[t] = dv*dv*acc;                  // self-loop contribution (write, not add)
}

// ---------------- GAT matmul: h = act(x)@W, plus fused al_s/al_d -----------
template<int K, bool FUSEIN>
__global__ __launch_bounds__(256) void k_mm_gat_t(
    const float* __restrict__ x, const float* __restrict__ bin,
    const float* __restrict__ W,
    const float* __restrict__ asrc, const float* __restrict__ adst,
    float* __restrict__ h, float* __restrict__ al_s, float* __restrict__ al_d)
{
    __shared__ float4 Ws[K*16];
    int tid = threadIdx.x;
    for (int r = tid; r < K*16; r += 256) Ws[r] = ((const float4*)W)[r];
    __syncthreads();
    int t = blockIdx.x*256 + tid;
    int i = t >> 6, j = t & 63;
    const float4* xr = (const float4*)(x + i*K);
    const float4* bv = (const float4*)bin;
    const float*  Wf = (const float*)Ws;
    float acc = 0.f;
    #pragma unroll
    for (int k4 = 0; k4 < K/4; k4++) {
        float4 xv = xr[k4];
        if constexpr (FUSEIN) {
            float4 b = bv[k4];
            xv.x = relu_(xv.x+b.x); xv.y = relu_(xv.y+b.y);
            xv.z = relu_(xv.z+b.z); xv.w = relu_(xv.w+b.w);
        }
        acc = fmaf(xv.x, Wf[(4*k4+0)*64 + j], acc);
        acc = fmaf(xv.y, Wf[(4*k4+1)*64 + j], acc);
        acc = fmaf(xv.z, Wf[(4*k4+2)*64 + j], acc);
        acc = fmaf(xv.w, Wf[(4*k4+3)*64 + j], acc);
    }
    h[t] = acc;
    // wave = one row i (lanes are j) -> shuffle-reduce the attention logits
    float ps = acc * asrc[j];
    float pd = acc * adst[j];
    for (int off = 32; off; off >>= 1) {
        ps += __shfl_down(ps, off, 64);
        pd += __shfl_down(pd, off, 64);
    }
    if (j == 0) { al_s[i] = ps; al_d[i] = pd; }
}

// ---------------- GCN3 matmul with fused 0.7*relu(xa+ba)+0.3*relu(xd+bd) ---
__global__ __launch_bounds__(256) void k_mm_gcn3(
    const float* __restrict__ xa, const float* __restrict__ ba,
    const float* __restrict__ xd, const float* __restrict__ bd,
    const float* __restrict__ W, const float* __restrict__ dinv,
    float* __restrict__ h, float* __restrict__ outacc)
{
    __shared__ float4 Ws[64*16];
    int tid = threadIdx.x;
    for (int r = tid; r < 64*16; r += 256) Ws[r] = ((const float4*)W)[r];
    __syncthreads();
    int t = blockIdx.x*256 + tid;
    int i = t >> 6, j = t & 63;
    const float4* xav = (const float4*)(xa + i*HD);
    const float4* xdv = (const float4*)(xd + i*HD);
    const float4* bav = (const float4*)ba;
    const float4* bdv = (const float4*)bd;
    const float*  Wf  = (const float*)Ws;
    float acc = 0.f;
    #pragma unroll
    for (int k4 = 0; k4 < 16; k4++) {
        float4 a = xav[k4], d = xdv[k4], b1 = bav[k4], b2 = bdv[k4];
        float v0 = 0.7f*relu_(a.x+b1.x) + 0.3f*relu_(d.x+b2.x);
        float v1 = 0.7f*relu_(a.y+b1.y) + 0.3f*relu_(d.y+b2.y);
        float v2 = 0.7f*relu_(a.z+b1.z) + 0.3f*relu_(d.z+b2.z);
        float v3 = 0.7f*relu_(a.w+b1.w) + 0.3f*relu_(d.w+b2.w);
        acc = fmaf(v0, Wf[(4*k4+0)*64 + j], acc);
        acc = fmaf(v1, Wf[(4*k4+1)*64 + j], acc);
        acc = fmaf(v2, Wf[(4*k4+2)*64 + j], acc);
        acc = fmaf(v3, Wf[(4*k4+3)*64 + j], acc);
    }
    h[t] = acc;
    float dv = dinv[i];
    outacc[t] = dv*dv*acc;
}

// ---------------- GCN edge scatter -----------------------------------------
__global__ __launch_bounds__(256) void k_gcn_scatter(
    const int* __restrict__ src, const int* __restrict__ dst,
    const float* __restrict__ dinv, const float* __restrict__ h,
    float* __restrict__ out)
{
    int t = blockIdx.x*256 + threadIdx.x;   // EV*64 threads; wave = one edge
    int e = t >> 6, k = t & 63;
    int s = src[e], d = dst[e];
    atomicAdd(&out[d*HD + k], dinv[s]*dinv[d]*h[s*HD + k]);
}

// ---------------- GAT edge pass: ex = exp(leaky_relu(e)), denom ------------
// (segment-max dropped: alpha = ex/denom is scale-invariant; |e| is O(10))
__global__ __launch_bounds__(256) void k_gat_edge(
    const int* __restrict__ src, const int* __restrict__ dst,
    const float* __restrict__ ew, const float* __restrict__ al_s,
    const float* __restrict__ al_d, const float* __restrict__ scal,
    int cidx, float* __restrict__ exbuf, float* __restrict__ denom)
{
    int e = blockIdx.x*256 + threadIdx.x;   // EV+NV threads
    int s, d; float w;
    if (e < EV) { s = src[e]; d = dst[e]; w = ew[e]; }
    else        { s = d = e - EV; w = scal[0]; }
    float v = al_s[s] + al_d[d] + w*scal[cidx];
    v = (v > 0.f) ? v : 0.2f*v;
    float ex = expf(v);
    exbuf[e] = ex;
    atomicAdd(&denom[d], ex);
}

__global__ __launch_bounds__(256) void k_gat_scatter(
    const int* __restrict__ src, const int* __restrict__ dst,
    const float* __restrict__ h, const float* __restrict__ exbuf,
    const float* __restrict__ denom, float* __restrict__ out)
{
    int t = blockIdx.x*256 + threadIdx.x;   // (EV+NV)*64 threads
    int e = t >> 6, k = t & 63;
    int s, d;
    if (e < EV) { s = src[e]; d = dst[e]; }
    else        { s = d = e - EV; }
    float alpha = exbuf[e] / denom[d];
    atomicAdd(&out[d*HD + k], alpha*h[s*HD + k]);
}

// ---------------- predictor head: h1 = relu(hin+bg3)@Wp1[:64] + bp1, h2 ----
__global__ __launch_bounds__(256) void k_pred(
    const float* __restrict__ hin, const float* __restrict__ bg3,
    const float* __restrict__ Wp1, const float* __restrict__ bp1,
    float* __restrict__ h1, float* __restrict__ h2)
{
    __shared__ float4 Ws[128*16];           // full Wp1: 128 x 64
    int tid = threadIdx.x;
    for (int r = tid; r < 128*16; r += 256) Ws[r] = ((const float4*)Wp1)[r];
    __syncthreads();
    int t = blockIdx.x*256 + tid;
    int i = t >> 6, j = t & 63;
    const float4* xr = (const float4*)(hin + i*HD);
    const float4* b3 = (const float4*)bg3;
    const float*  Wf = (const float*)Ws;
    float a1 = 0.f, a2 = 0.f;
    #pragma unroll
    for (int k4 = 0; k4 < 16; k4++) {
        float4 xv = xr[k4];
        float4 b = b3[k4];
        xv.x = relu_(xv.x+b.x); xv.y = relu_(xv.y+b.y);
        xv.z = relu_(xv.z+b.z); xv.w = relu_(xv.w+b.w);
        a1 = fmaf(xv.x, Wf[(4*k4+0)*64 + j], a1);
        a2 = fmaf(xv.x, Wf[(64+4*k4+0)*64 + j], a2);
        a1 = fmaf(xv.y, Wf[(4*k4+1)*64 + j], a1);
        a2 = fmaf(xv.y, Wf[(64+4*k4+1)*64 + j], a2);
        a1 = fmaf(xv.z, Wf[(4*k4+2)*64 + j], a1);
        a2 = fmaf(xv.z, Wf[(64+4*k4+2)*64 + j], a2);
        a1 = fmaf(xv.w, Wf[(4*k4+3)*64 + j], a1);
        a2 = fmaf(xv.w, Wf[(64+4*k4+3)*64 + j], a2);
    }
    h1[t] = a1 + bp1[j];
    h2[t] = a2;
}

// ---------------- all-pairs: 32x32 tile, 2x2 per thread --------------------
__global__ __launch_bounds__(256) void k_pairs(
    const float4* __restrict__ h14, const float4* __restrict__ h24,
    const float4* __restrict__ w24, const float* __restrict__ bp2,
    float* __restrict__ out)
{
    __shared__ float4 s1[32*17], s2[32*17], w2s[16];
    int tid = threadIdx.x;
    int i0 = blockIdx.y*32, j0 = blockIdx.x*32;
    for (int r = tid; r < 512; r += 256) {
        int row = r >> 4, c = r & 15;
        s1[row*17 + c] = h14[(i0+row)*16 + c];
        s2[row*17 + c] = h24[(j0+row)*16 + c];
    }
    if (tid < 16) w2s[tid] = w24[tid];
    __syncthreads();
    int ty = tid >> 4, tx = tid & 15;
    float a00 = 0.f, a01 = 0.f, a10 = 0.f, a11 = 0.f;
    #pragma unroll
    for (int k4 = 0; k4 < 16; k4++) {
        float4 va0 = s1[ty*17 + k4],     va1 = s1[(ty+16)*17 + k4];
        float4 vb0 = s2[tx*17 + k4],     vb1 = s2[(tx+16)*17 + k4];
        float4 wv  = w2s[k4];
#define STEP(c) \
        a00 = fmaf(fmaxf(va0.c+vb0.c, 0.f), wv.c, a00); \
        a01 = fmaf(fmaxf(va0.c+vb1.c, 0.f), wv.c, a01); \
        a10 = fmaf(fmaxf(va1.c+vb0.c, 0.f), wv.c, a10); \
        a11 = fmaf(fmaxf(va1.c+vb1.c, 0.f), wv.c, a11);
        STEP(x) STEP(y) STEP(z) STEP(w)
#undef STEP
    }
    float bb = bp2[0];
    int i = i0 + ty, jj = j0 + tx;
    out[i*NV + jj]          = 1.f/(1.f + expf(-(a00+bb)));
    out[i*NV + jj + 16]     = 1.f/(1.f + expf(-(a01+bb)));
    out[(i+16)*NV + jj]     = 1.f/(1.f + expf(-(a10+bb)));
    out[(i+16)*NV + jj + 16]= 1.f/(1.f + expf(-(a11+bb)));
}

// ---------------------------------------------------------------------------
extern "C" void kernel_launch(void* const* d_in, const int* in_sizes, int n_in,
                              void* d_out, int out_size, void* d_ws, size_t ws_size,
                              hipStream_t stream)
{
    const float* x    = (const float*)d_in[0];
    const int*   ei_a = (const int*)d_in[1];
    const int*   ei_d = (const int*)d_in[2];
    const float* ew   = (const float*)d_in[3];
    const float* Wg1  = (const float*)d_in[4];
    const float* bg1  = (const float*)d_in[5];
    const float* Wt1  = (const float*)d_in[6];
    const float* as1  = (const float*)d_in[7];
    const float* ad1  = (const float*)d_in[8];
    const float* we1  = (const float*)d_in[9];
    const float* ae1  = (const float*)d_in[10];
    const float* bt1  = (const float*)d_in[11];
    const float* Wg2  = (const float*)d_in[12];
    const float* bg2  = (const float*)d_in[13];
    const float* Wt2  = (const float*)d_in[14];
    const float* as2  = (const float*)d_in[15];
    const float* ad2  = (const float*)d_in[16];
    const float* we2  = (const float*)d_in[17];
    const float* ae2  = (const float*)d_in[18];
    const float* bt2  = (const float*)d_in[19];
    const float* Wg3  = (const float*)d_in[20];
    const float* bg3  = (const float*)d_in[21];
    const float* Wp1  = (const float*)d_in[22];
    const float* bp1  = (const float*)d_in[23];
    const float* Wp2  = (const float*)d_in[24];
    const float* bp2  = (const float*)d_in[25];
    float* out = (float*)d_out;

    const int* sa = ei_a;
    const int* da = ei_a + EV;
    const int* sd = ei_d;
    const int* dd = ei_d + EV;

    // workspace layout (floats). [0, 134144) is the zero-init region.
    float* W = (float*)d_ws;
    float* deg    = W + 0;          // 1024
    float* denom1 = W + 1024;       // 1024
    float* denom2 = W + 2048;       // 1024
    float* xd1    = W + 3072;       // 65536
    float* xd2    = W + 68608;      // 65536  (zero region ends at 134144)
    float* scal   = W + 134144;     // 8
    float* dinv   = W + 134152;     // 1024
    float* al_s   = W + 135176;     // 1024
    float* al_d   = W + 136200;     // 1024
    float* exbuf  = W + 137224;     // 17408
    float* hg     = W + 154632;     // 65536 (GCN-path pre-activation product)
    float* hga    = W + 220168;     // 65536 (GAT-path)
    float* xa1    = W + 285704;     // 65536
    float* xa2    = W + 351240;     // 65536
    float* hfin   = W + 416776;     // 65536
    float* h1     = W + 482312;     // 65536
    float* h2     = W + 547848;     // 65536

    hipMemsetAsync(W, 0, 134144*sizeof(float), stream);
    k_deg<<<EV/256, 256, 0, stream>>>(da, deg);
    k_pre<<<1, 256, 0, stream>>>(ew, we1, ae1, we2, ae2, deg, scal, dinv);

    // ---- GCN1: x -> xa1 (raw; bias+relu folded into GCN2 load)
    k_mm_gcn_t<FIN,false><<<256, 256, 0, stream>>>(x, nullptr, Wg1, dinv, hg, xa1);
    k_gcn_scatter<<<EV*HD/256, 256, 0, stream>>>(sa, da, dinv, hg, xa1);

    // ---- GAT1: x -> xd1 (raw)
    k_mm_gat_t<FIN,false><<<256, 256, 0, stream>>>(x, nullptr, Wt1, as1, ad1, hga, al_s, al_d);
    k_gat_edge<<<(EV+NV)/256, 256, 0, stream>>>(sd, dd, ew, al_s, al_d, scal, 1, exbuf, denom1);
    k_gat_scatter<<<(EV+NV)*HD/256, 256, 0, stream>>>(sd, dd, hga, exbuf, denom1, xd1);

    // ---- GCN2: relu(xa1+bg1) -> xa2 (raw)
    k_mm_gcn_t<HD,true><<<256, 256, 0, stream>>>(xa1, bg1, Wg2, dinv, hg, xa2);
    k_gcn_scatter<<<EV*HD/256, 256, 0, stream>>>(sa, da, dinv, hg, xa2);

    // ---- GAT2: relu(xd1+bt1) -> xd2 (raw)
    k_mm_gat_t<HD,true><<<256, 256, 0, stream>>>(xd1, bt1, Wt2, as2, ad2, hga, al_s, al_d);
    k_gat_edge<<<(EV+NV)/256, 256, 0, stream>>>(sd, dd, ew, al_s, al_d, scal, 2, exbuf, denom2);
    k_gat_scatter<<<(EV+NV)*HD/256, 256, 0, stream>>>(sd, dd, hga, exbuf, denom2, xd2);

    // ---- GCN3: 0.7*relu(xa2+bg2)+0.3*relu(xd2+bt2) -> hfin (raw)
    k_mm_gcn3<<<256, 256, 0, stream>>>(xa2, bg2, xd2, bt2, Wg3, dinv, hg, hfin);
    k_gcn_scatter<<<EV*HD/256, 256, 0, stream>>>(sa, da, dinv, hg, hfin);

    // ---- predictor
    k_pred<<<256, 256, 0, stream>>>(hfin, bg3, Wp1, bp1, h1, h2);
    k_pairs<<<dim3(NV/32, NV/32), 256, 0, stream>>>(
        (const float4*)h1, (const float4*)h2, (const float4*)Wp2, bp2, out);
}

// Round 3
// 202.119 us; speedup vs baseline: 1.6585x; 1.0177x over previous
//
#include <hip/hip_runtime.h>

constexpr int NV  = 1024;   // nodes
constexpr int EV  = 16384;  // edges
constexpr int FIN = 128;
constexpr int HD  = 64;

__device__ __forceinline__ float relu_(float v){ return fmaxf(v, 0.f); }

// ---------------- CSR build step 1: degree count + ew sum ------------------
__global__ __launch_bounds__(256) void k_count(
    const int* __restrict__ da, const int* __restrict__ dd,
    const float* __restrict__ ew,
    int* __restrict__ deg_a, int* __restrict__ deg_d, float* __restrict__ scal)
{
    int e = blockIdx.x*256 + threadIdx.x;   // exactly EV threads
    atomicAdd(&deg_a[da[e]], 1);
    atomicAdd(&deg_d[dd[e]], 1);
    float w = ew[e];
    for (int off = 32; off; off >>= 1) w += __shfl_down(w, off, 64);
    if ((threadIdx.x & 63) == 0) atomicAdd(&scal[3], w);
}

// ---------------- CSR build step 2: prefix scan (1 block) + scalars --------
__global__ __launch_bounds__(1024) void k_scan(
    const int* __restrict__ deg_a, const int* __restrict__ deg_d,
    const float* __restrict__ we1, const float* __restrict__ ae1,
    const float* __restrict__ we2, const float* __restrict__ ae2,
    int* __restrict__ rpa, int* __restrict__ rpd,
    int* __restrict__ cur_a, int* __restrict__ cur_d,
    float* __restrict__ dinv, float* __restrict__ scal)
{
    __shared__ int sa_[1024], sd_[1024];
    int t = threadIdx.x;
    int dega = deg_a[t], degd = deg_d[t];
    sa_[t] = dega; sd_[t] = degd;
    __syncthreads();
    for (int off = 1; off < 1024; off <<= 1) {
        int va = (t >= off) ? sa_[t-off] : 0;
        int vd = (t >= off) ? sd_[t-off] : 0;
        __syncthreads();
        sa_[t] += va; sd_[t] += vd;
        __syncthreads();
    }
    rpa[t+1] = sa_[t]; rpd[t+1] = sd_[t];
    cur_a[t] = sa_[t] - dega; cur_d[t] = sd_[t] - degd;
    if (t == 0) { rpa[0] = 0; rpd[0] = 0; }
    dinv[t] = rsqrtf((float)dega + 1.0f);   // +1 = GCN self-loop
    if (t < 64) {
        float p1 = we1[t]*ae1[t];
        float p2 = we2[t]*ae2[t];
        for (int off = 32; off; off >>= 1) {
            p1 += __shfl_down(p1, off, 64);
            p2 += __shfl_down(p2, off, 64);
        }
        if (t == 0) { scal[1] = p1; scal[2] = p2; scal[0] = scal[3] / (float)EV; }
    }
}

// ---------------- CSR build step 3: fill slots -----------------------------
__global__ __launch_bounds__(256) void k_fill(
    const int* __restrict__ sa, const int* __restrict__ da,
    const int* __restrict__ sd, const int* __restrict__ dd,
    const float* __restrict__ ew,
    int* __restrict__ cur_a, int* __restrict__ cur_d,
    int* __restrict__ csrc_a, int* __restrict__ csrc_d, float* __restrict__ cw_d)
{
    int e = blockIdx.x*256 + threadIdx.x;   // exactly EV threads
    int pa = atomicAdd(&cur_a[da[e]], 1);
    csrc_a[pa] = sa[e];
    int pd = atomicAdd(&cur_d[dd[e]], 1);
    csrc_d[pd] = sd[e];
    cw_d[pd]   = ew[e];
}

// ---------------- dense matmul h = x@W (W staged in LDS) -------------------
template<int K>
__global__ __launch_bounds__(256) void k_mm_t(
    const float* __restrict__ x, const float* __restrict__ W,
    float* __restrict__ h)
{
    __shared__ float4 Ws[K*16];             // K x 64 floats
    int tid = threadIdx.x;
    for (int r = tid; r < K*16; r += 256) Ws[r] = ((const float4*)W)[r];
    __syncthreads();
    int t = blockIdx.x*256 + tid;
    int i = t >> 6, j = t & 63;
    const float4* xr = (const float4*)(x + i*K);
    const float*  Wf = (const float*)Ws;
    float acc = 0.f;
    #pragma unroll
    for (int k4 = 0; k4 < K/4; k4++) {
        float4 xv = xr[k4];
        acc = fmaf(xv.x, Wf[(4*k4+0)*64 + j], acc);
        acc = fmaf(xv.y, Wf[(4*k4+1)*64 + j], acc);
        acc = fmaf(xv.z, Wf[(4*k4+2)*64 + j], acc);
        acc = fmaf(xv.w, Wf[(4*k4+3)*64 + j], acc);
    }
    h[t] = acc;
}

// ---------------- GAT matmul + fused attention logits ----------------------
template<int K>
__global__ __launch_bounds__(256) void k_mm_gat_t(
    const float* __restrict__ x, const float* __restrict__ W,
    const float* __restrict__ asrc, const float* __restrict__ adst,
    float* __restrict__ h, float* __restrict__ al_s, float* __restrict__ al_d)
{
    __shared__ float4 Ws[K*16];
    int tid = threadIdx.x;
    for (int r = tid; r < K*16; r += 256) Ws[r] = ((const float4*)W)[r];
    __syncthreads();
    int t = blockIdx.x*256 + tid;
    int i = t >> 6, j = t & 63;
    const float4* xr = (const float4*)(x + i*K);
    const float*  Wf = (const float*)Ws;
    float acc = 0.f;
    #pragma unroll
    for (int k4 = 0; k4 < K/4; k4++) {
        float4 xv = xr[k4];
        acc = fmaf(xv.x, Wf[(4*k4+0)*64 + j], acc);
        acc = fmaf(xv.y, Wf[(4*k4+1)*64 + j], acc);
        acc = fmaf(xv.z, Wf[(4*k4+2)*64 + j], acc);
        acc = fmaf(xv.w, Wf[(4*k4+3)*64 + j], acc);
    }
    h[t] = acc;
    float ps = acc * asrc[j];
    float pd = acc * adst[j];
    for (int off = 32; off; off >>= 1) {
        ps += __shfl_down(ps, off, 64);
        pd += __shfl_down(pd, off, 64);
    }
    if (j == 0) { al_s[i] = ps; al_d[i] = pd; }
}

// ---------------- GCN3 matmul: (0.7*xa2 + 0.3*xd2)@W -----------------------
__global__ __launch_bounds__(256) void k_mm3(
    const float* __restrict__ xa, const float* __restrict__ xd,
    const float* __restrict__ W, float* __restrict__ h)
{
    __shared__ float4 Ws[64*16];
    int tid = threadIdx.x;
    for (int r = tid; r < 64*16; r += 256) Ws[r] = ((const float4*)W)[r];
    __syncthreads();
    int t = blockIdx.x*256 + tid;
    int i = t >> 6, j = t & 63;
    const float4* xav = (const float4*)(xa + i*HD);
    const float4* xdv = (const float4*)(xd + i*HD);
    const float*  Wf  = (const float*)Ws;
    float acc = 0.f;
    #pragma unroll
    for (int k4 = 0; k4 < 16; k4++) {
        float4 a = xav[k4], d = xdv[k4];
        acc = fmaf(0.7f*a.x + 0.3f*d.x, Wf[(4*k4+0)*64 + j], acc);
        acc = fmaf(0.7f*a.y + 0.3f*d.y, Wf[(4*k4+1)*64 + j], acc);
        acc = fmaf(0.7f*a.z + 0.3f*d.z, Wf[(4*k4+2)*64 + j], acc);
        acc = fmaf(0.7f*a.w + 0.3f*d.w, Wf[(4*k4+3)*64 + j], acc);
    }
    h[t] = acc;
}

// ---------------- GCN gather: out = relu(dinv_d*(dinv_d*h_d + sum) + b) ----
__global__ __launch_bounds__(256) void k_gather_gcn(
    const int* __restrict__ rp, const int* __restrict__ csrc,
    const float* __restrict__ dinv, const float* __restrict__ h,
    const float* __restrict__ b, float* __restrict__ out)
{
    int d = blockIdx.x*4 + (threadIdx.x >> 6);   // wave = one dst node
    int k = threadIdx.x & 63;
    float dv = dinv[d];
    float acc = dv * h[d*HD + k];                // self-loop (dv factored out)
    int p0 = rp[d], p1 = rp[d+1];
    for (int p = p0; p < p1; ++p) {
        int s = csrc[p];
        acc = fmaf(dinv[s], h[s*HD + k], acc);
    }
    out[d*HD + k] = relu_(fmaf(dv, acc, b[k]));
}

// ---------------- GAT gather: softmax + weighted sum, fused ----------------
// (segment-max dropped: alpha = ex/den is scale-invariant; |e| is O(10))
__global__ __launch_bounds__(256) void k_gather_gat(
    const int* __restrict__ rp, const int* __restrict__ csrc,
    const float* __restrict__ cw, const float* __restrict__ al_s,
    const float* __restrict__ al_d, const float* __restrict__ scal, int cidx,
    const float* __restrict__ h, const float* __restrict__ b,
    float* __restrict__ out)
{
    int d = blockIdx.x*4 + (threadIdx.x >> 6);
    int k = threadIdx.x & 63;
    float aD = al_d[d];
    float c  = scal[cidx];
    float es = al_s[d] + aD + scal[0]*c;         // self-loop, ew = mean
    es = expf((es > 0.f) ? es : 0.2f*es);
    float num = es * h[d*HD + k];
    float den = es;
    int p0 = rp[d], p1 = rp[d+1];
    for (int p = p0; p < p1; ++p) {
        int s = csrc[p];
        float e = al_s[s] + aD + cw[p]*c;
        float ex = expf((e > 0.f) ? e : 0.2f*e);
        den += ex;
        num = fmaf(ex, h[s*HD + k], num);
    }
    out[d*HD + k] = relu_(num/den + b[k]);
}

// ---------------- predictor head: h1 = hin@Wp1[:64]+bp1, h2 = hin@Wp1[64:] -
__global__ __launch_bounds__(256) void k_pred(
    const float* __restrict__ hin, const float* __restrict__ Wp1,
    const float* __restrict__ bp1, float* __restrict__ h1,
    float* __restrict__ h2)
{
    __shared__ float4 Ws[128*16];                // full Wp1: 128 x 64
    int tid = threadIdx.x;
    for (int r = tid; r < 128*16; r += 256) Ws[r] = ((const float4*)Wp1)[r];
    __syncthreads();
    int t = blockIdx.x*256 + tid;
    int i = t >> 6, j = t & 63;
    const float4* xr = (const float4*)(hin + i*HD);
    const float*  Wf = (const float*)Ws;
    float a1 = 0.f, a2 = 0.f;
    #pragma unroll
    for (int k4 = 0; k4 < 16; k4++) {
        float4 xv = xr[k4];
        a1 = fmaf(xv.x, Wf[(4*k4+0)*64 + j], a1);
        a2 = fmaf(xv.x, Wf[(64+4*k4+0)*64 + j], a2);
        a1 = fmaf(xv.y, Wf[(4*k4+1)*64 + j], a1);
        a2 = fmaf(xv.y, Wf[(64+4*k4+1)*64 + j], a2);
        a1 = fmaf(xv.z, Wf[(4*k4+2)*64 + j], a1);
        a2 = fmaf(xv.z, Wf[(64+4*k4+2)*64 + j], a2);
        a1 = fmaf(xv.w, Wf[(4*k4+3)*64 + j], a1);
        a2 = fmaf(xv.w, Wf[(64+4*k4+3)*64 + j], a2);
    }
    h1[t] = a1 + bp1[j];
    h2[t] = a2;
}

// ---------------- all-pairs: 32x32 tile, 2x2 per thread --------------------
__global__ __launch_bounds__(256) void k_pairs(
    const float4* __restrict__ h14, const float4* __restrict__ h24,
    const float4* __restrict__ w24, const float* __restrict__ bp2,
    float* __restrict__ out)
{
    __shared__ float4 s1[32*17], s2[32*17], w2s[16];
    int tid = threadIdx.x;
    int i0 = blockIdx.y*32, j0 = blockIdx.x*32;
    for (int r = tid; r < 512; r += 256) {
        int row = r >> 4, c = r & 15;
        s1[row*17 + c] = h14[(i0+row)*16 + c];
        s2[row*17 + c] = h24[(j0+row)*16 + c];
    }
    if (tid < 16) w2s[tid] = w24[tid];
    __syncthreads();
    int ty = tid >> 4, tx = tid & 15;
    float a00 = 0.f, a01 = 0.f, a10 = 0.f, a11 = 0.f;
    #pragma unroll
    for (int k4 = 0; k4 < 16; k4++) {
        float4 va0 = s1[ty*17 + k4],     va1 = s1[(ty+16)*17 + k4];
        float4 vb0 = s2[tx*17 + k4],     vb1 = s2[(tx+16)*17 + k4];
        float4 wv  = w2s[k4];
#define STEP(c) \
        a00 = fmaf(fmaxf(va0.c+vb0.c, 0.f), wv.c, a00); \
        a01 = fmaf(fmaxf(va0.c+vb1.c, 0.f), wv.c, a01); \
        a10 = fmaf(fmaxf(va1.c+vb0.c, 0.f), wv.c, a10); \
        a11 = fmaf(fmaxf(va1.c+vb1.c, 0.f), wv.c, a11);
        STEP(x) STEP(y) STEP(z) STEP(w)
#undef STEP
    }
    float bb = bp2[0];
    int i = i0 + ty, jj = j0 + tx;
    out[i*NV + jj]           = 1.f/(1.f + expf(-(a00+bb)));
    out[i*NV + jj + 16]      = 1.f/(1.f + expf(-(a01+bb)));
    out[(i+16)*NV + jj]      = 1.f/(1.f + expf(-(a10+bb)));
    out[(i+16)*NV + jj + 16] = 1.f/(1.f + expf(-(a11+bb)));
}

// ---------------------------------------------------------------------------
extern "C" void kernel_launch(void* const* d_in, const int* in_sizes, int n_in,
                              void* d_out, int out_size, void* d_ws, size_t ws_size,
                              hipStream_t stream)
{
    const float* x    = (const float*)d_in[0];
    const int*   ei_a = (const int*)d_in[1];
    const int*   ei_d = (const int*)d_in[2];
    const float* ew   = (const float*)d_in[3];
    const float* Wg1  = (const float*)d_in[4];
    const float* bg1  = (const float*)d_in[5];
    const float* Wt1  = (const float*)d_in[6];
    const float* as1  = (const float*)d_in[7];
    const float* ad1  = (const float*)d_in[8];
    const float* we1  = (const float*)d_in[9];
    const float* ae1  = (const float*)d_in[10];
    const float* bt1  = (const float*)d_in[11];
    const float* Wg2  = (const float*)d_in[12];
    const float* bg2  = (const float*)d_in[13];
    const float* Wt2  = (const float*)d_in[14];
    const float* as2  = (const float*)d_in[15];
    const float* ad2  = (const float*)d_in[16];
    const float* we2  = (const float*)d_in[17];
    const float* ae2  = (const float*)d_in[18];
    const float* bt2  = (const float*)d_in[19];
    const float* Wg3  = (const float*)d_in[20];
    const float* bg3  = (const float*)d_in[21];
    const float* Wp1  = (const float*)d_in[22];
    const float* bp1  = (const float*)d_in[23];
    const float* Wp2  = (const float*)d_in[24];
    const float* bp2  = (const float*)d_in[25];
    float* out = (float*)d_out;

    const int* sa = ei_a;
    const int* da = ei_a + EV;
    const int* sd = ei_d;
    const int* dd = ei_d + EV;

    // workspace layout (4-byte units). [0, 4104) is the zero-init region.
    float* W = (float*)d_ws;
    int*   deg_a  = (int*)(W + 0);       // 1024
    int*   deg_d  = (int*)(W + 1024);    // 1024
    int*   cur_a  = (int*)(W + 2048);    // 1024
    int*   cur_d  = (int*)(W + 3072);    // 1024
    float* scal   = W + 4096;            // 8 (scal[3] = ew running sum)
    int*   rpa    = (int*)(W + 4104);    // 1025
    int*   rpd    = (int*)(W + 5129);    // 1025
    float* dinv   = W + 6154;            // 1024
    float* al_s   = W + 7178;            // 1024
    float* al_d   = W + 8202;            // 1024
    int*   csrc_a = (int*)(W + 9226);    // 16384
    int*   csrc_d = (int*)(W + 25610);   // 16384
    float* cw_d   = W + 41994;           // 16384
    float* hg     = W + 58380;           // 65536 (16B aligned)
    float* hga    = W + 123916;          // 65536
    float* xa1    = W + 189452;          // 65536
    float* xd1    = W + 254988;          // 65536
    float* xa2    = W + 320524;          // 65536
    float* xd2    = W + 386060;          // 65536
    float* hfin   = W + 451596;          // 65536
    float* h1     = W + 517132;          // 65536
    float* h2     = W + 582668;          // 65536

    hipMemsetAsync(W, 0, 4104*sizeof(float), stream);

    // ---- CSR build (both graphs) + scalars
    k_count<<<EV/256, 256, 0, stream>>>(da, dd, ew, deg_a, deg_d, scal);
    k_scan<<<1, 1024, 0, stream>>>(deg_a, deg_d, we1, ae1, we2, ae2,
                                   rpa, rpd, cur_a, cur_d, dinv, scal);
    k_fill<<<EV/256, 256, 0, stream>>>(sa, da, sd, dd, ew,
                                       cur_a, cur_d, csrc_a, csrc_d, cw_d);

    // ---- GCN1: x -> xa1 (activated)
    k_mm_t<FIN><<<256, 256, 0, stream>>>(x, Wg1, hg);
    k_gather_gcn<<<NV/4, 256, 0, stream>>>(rpa, csrc_a, dinv, hg, bg1, xa1);

    // ---- GAT1: x -> xd1 (activated)
    k_mm_gat_t<FIN><<<256, 256, 0, stream>>>(x, Wt1, as1, ad1, hga, al_s, al_d);
    k_gather_gat<<<NV/4, 256, 0, stream>>>(rpd, csrc_d, cw_d, al_s, al_d, scal, 1,
                                           hga, bt1, xd1);

    // ---- GCN2: xa1 -> xa2 (activated)
    k_mm_t<HD><<<256, 256, 0, stream>>>(xa1, Wg2, hg);
    k_gather_gcn<<<NV/4, 256, 0, stream>>>(rpa, csrc_a, dinv, hg, bg2, xa2);

    // ---- GAT2: xd1 -> xd2 (activated)
    k_mm_gat_t<HD><<<256, 256, 0, stream>>>(xd1, Wt2, as2, ad2, hga, al_s, al_d);
    k_gather_gat<<<NV/4, 256, 0, stream>>>(rpd, csrc_d, cw_d, al_s, al_d, scal, 2,
                                           hga, bt2, xd2);

    // ---- GCN3: 0.7*xa2+0.3*xd2 -> hfin (activated)
    k_mm3<<<256, 256, 0, stream>>>(xa2, xd2, Wg3, hg);
    k_gather_gcn<<<NV/4, 256, 0, stream>>>(rpa, csrc_a, dinv, hg, bg3, hfin);

    // ---- predictor
    k_pred<<<256, 256, 0, stream>>>(hfin, Wp1, bp1, h1, h2);
    k_pairs<<<dim3(NV/32, NV/32), 256, 0, stream>>>(
        (const float4*)h1, (const float4*)h2, (const float4*)Wp2, bp2, out);
}